// Round 5
// baseline (204.443 us; speedup 1.0000x reference)
//
#include <hip/hip_runtime.h>

// Causal MHA: B=2, H=16, S=2048, DH=64. fp32 in/out. bf16 MFMA inside.
// R14: ZERO-BARRIER main loop. R12 vs R13: two structurally different
// kernels (different LDS traffic, MFMA count, conflicts) both land at
// 43.6us with nothing saturated (MFMA 26%, VALU 37%, HBM 11%, Occ 32%).
// Shared invariant = per-tile __syncthreads lockstep across 6+ waves/SIMD:
// every tile pays the slowest wave's jitter + staging drain. Fix: drop LDS
// staging of K/V entirely -- both are consumed as fragments whose global
// layout is already per-lane contiguous (K row-major: ak = 16B/lane;
// V^T from prep: av = 8B/lane). Each wave loads fragments DIRECTLY from
// global (L2-resident working set) with 1-tile register prefetch. Waves
// share nothing in the main loop -> no barriers at all. LDS = 18.4KB only
// (Q-stage overlaid with R13's proven cross-kslice reduction epilogue).
// __launch_bounds__(512,4) caps VGPR 128 -> ~16 waves/CU, all async.
// Kept from R13: (kslice,qhalf) wave roles, in-register P via St D-layout ==
// K16 B-fragment + zero-padded K=32 MFMA, l via padded ones-MFMA, reduction
// epilogue. Kept from earlier: selective split-k + LPT (R11), fast_exp2,
// fixed-max softmax (partials combine exactly), -M2 in C-init, v_perm pack,
// prep (bf16 Q*0.125*log2e, K, V^T), analytic causal mask. Fallbacks same.

#define S_LEN  2048
#define DHDIM  64
#define NHEADS 32   // B*H
#define LDP    72   // padded LDS row length in shorts (144B = 9*16B)
#define M2     23.083120654223414f   // 16 * log2(e)
#define QSCALE 0.18033688011117658f  // 0.125 * log2(e)

typedef __attribute__((ext_vector_type(8))) short bf16x8;
typedef __attribute__((ext_vector_type(4))) float f32x4;

// static LPT schedule: 48 items per bh, descending length.
// splits for qt in [16,31] (kmid=(qt+2)>>1), wholes for qt in [0,15].
__device__ __constant__ unsigned char T_QT[48] = {
    31,31,30,15, 30,29,29,28,14, 28,27,27,26,13, 26,25,25,24,12,
    24,23,23,22,11, 22,21,21,20,10, 20,19,19,18,9, 18,17,17,16,8,
    16,7, 6,5,4,3,2,1,0};
__device__ __constant__ unsigned char T_K0[48] = {
    0,16,0,0, 16,0,15,0,0, 15,0,14,0,0, 14,0,13,0,0,
    13,0,12,0,0, 12,0,11,0,0, 11,0,10,0,0, 10,0,9,0,0,
    9,0, 0,0,0,0,0,0,0};
__device__ __constant__ unsigned char T_K1[48] = {
    16,32,16,16, 31,15,30,15,15, 29,14,28,14,14, 27,13,26,13,13,
    25,12,24,12,12, 23,11,22,11,11, 21,10,20,10,10, 19,9,18,9,9,
    17,8, 7,6,5,4,3,2,1};

__device__ __forceinline__ float fast_exp2(float x) {
#if __has_builtin(__builtin_amdgcn_exp2f)
    return __builtin_amdgcn_exp2f(x);
#else
    return exp2f(x);
#endif
}
__device__ __forceinline__ unsigned short f2bf(float f) { // RNE
    unsigned u = __float_as_uint(f);
    return (unsigned short)((u + 0x7fffu + ((u >> 16) & 1u)) >> 16);
}
__device__ __forceinline__ void ld8(const float* p, float* f) {
    float4 a = *(const float4*)p, b = *(const float4*)(p + 4);
    f[0]=a.x; f[1]=a.y; f[2]=a.z; f[3]=a.w; f[4]=b.x; f[5]=b.y; f[6]=b.z; f[7]=b.w;
}
__device__ __forceinline__ uint4 pack8(const float* f, float scale) {
    union { uint4 v; unsigned short s[8]; } w;
    #pragma unroll
    for (int j = 0; j < 8; j++) w.s[j] = f2bf(f[j] * scale);
    return w.v;
}
// combine high-16s of two floats into one dword: [lo16=a.hi16, hi16=b.hi16]
__device__ __forceinline__ unsigned packhi(float a, float b) {
#if __has_builtin(__builtin_amdgcn_perm)
    return __builtin_amdgcn_perm(__float_as_uint(b), __float_as_uint(a), 0x07060302u);
#else
    return (__float_as_uint(a) >> 16) | (__float_as_uint(b) & 0xffff0000u);
#endif
}
// bf16x8 with low 4 shorts from two dwords, high 4 = 0 (zero-padded K=16)
__device__ __forceinline__ bf16x8 pad4(unsigned lo, unsigned hi) {
    union { unsigned u[4]; bf16x8 v; } w;
    w.u[0] = lo; w.u[1] = hi; w.u[2] = 0u; w.u[3] = 0u;
    return w.v;
}
__device__ __forceinline__ bf16x8 as_bf16x8(uint4 v) {
    union { uint4 u; bf16x8 b; } w; w.u = v; return w.b;
}

// ---- pre-pass: per block (st, bh): V 64x64 tile -> bf16 V^T tile, plus a
// 4096-elem chunk of Q (scaled) and K -> bf16.
__global__ __launch_bounds__(256) void prep(
    const float* __restrict__ Qf, const float* __restrict__ Kf,
    const float* __restrict__ Vf, unsigned short* __restrict__ qb,
    unsigned short* __restrict__ kb, unsigned short* __restrict__ vtb)
{
    const int st = blockIdx.x, bh = blockIdx.y;
    __shared__ unsigned lt32[64][LDP / 2];   // dword view: 36 dwords/row
    const float* vp = Vf + ((size_t)bh * S_LEN + st * 64) * DHDIM;
    {
        const int c = threadIdx.x;
        const int sp = c >> 3;            // s-pair index 0..31
        const int d0 = (c & 7) * 8;
        float fa[8], fb[8];
        ld8(vp + (2 * sp) * DHDIM + d0, fa);
        ld8(vp + (2 * sp + 1) * DHDIM + d0, fb);
        #pragma unroll
        for (int j = 0; j < 8; j++) {
            int d = d0 + j;
            int colw = (sp & 3) | ((((sp >> 2) ^ (d >> 3)) & 7) << 2);
            lt32[d][colw] = (unsigned)f2bf(fa[j]) | ((unsigned)f2bf(fb[j]) << 16);
        }
    }
    size_t off = ((size_t)(bh * 32 + st) * 4096) + (size_t)threadIdx.x * 16;
    float f[8];
    ld8(Qf + off, f);     *(uint4*)(qb + off)     = pack8(f, QSCALE);
    ld8(Qf + off + 8, f); *(uint4*)(qb + off + 8) = pack8(f, QSCALE);
    ld8(Kf + off, f);     *(uint4*)(kb + off)     = pack8(f, 1.0f);
    ld8(Kf + off + 8, f); *(uint4*)(kb + off + 8) = pack8(f, 1.0f);
    __syncthreads();
    unsigned short* op = vtb + (size_t)bh * DHDIM * S_LEN + st * 64;
    for (int c = threadIdx.x; c < 512; c += 256) {
        int d = c >> 3, q = c & 7;
        int colw = ((q ^ (d >> 3)) & 7) << 2;
        *(uint4*)(op + (size_t)d * S_LEN + q * 8) = *(const uint4*)&lt32[d][colw];
    }
}

// ---- main: 512 threads, 8 waves = (kslice, qhalf). In-register P.
// NO LDS staging, NO barriers in the main loop: K/V fragments come straight
// from global (L2-resident) with a 1-tile register prefetch.
__global__ __launch_bounds__(512, 4) void fattn_splitk(
    const unsigned short* __restrict__ Qp, const unsigned short* __restrict__ Kp,
    const unsigned short* __restrict__ Vp,
    float* __restrict__ pO, float* __restrict__ pL, float* __restrict__ O)
{
    __shared__ float fs[4608];                 // 18.4 KB: Q-stage overlay + reduction
    unsigned short (*qs)[LDP] = (unsigned short(*)[LDP])fs;

    const int bh   = blockIdx.x;           // 0..31
    const int rank = blockIdx.y;           // 0..47, longest-first
    const int qt   = T_QT[rank];
    const int k0   = T_K0[rank];
    const int k1   = T_K1[rank];
    const bool whole = (k1 - k0 == qt + 1);

    const int tid  = threadIdx.x;
    const int wave = tid >> 6, lane = tid & 63;
    const int quad = lane >> 4, l16 = lane & 15;
    const int kslice = wave & 3, qhalf = wave >> 2;

    // ---- stage Q tile (one uint4/thread), load bq fragments into regs
    {
        const unsigned short* src = Qp + ((size_t)bh * S_LEN + qt * 64) * DHDIM;
        int row = tid >> 3, c8 = (tid & 7) * 8;
        *(uint4*)&qs[row][c8] = *(const uint4*)(src + row * DHDIM + c8);
    }
    __syncthreads();
    const bf16x8 bq00 = *(const bf16x8*)&qs[qhalf * 32 + l16][quad * 8];
    const bf16x8 bq01 = *(const bf16x8*)&qs[qhalf * 32 + l16][32 + quad * 8];
    const bf16x8 bq10 = *(const bf16x8*)&qs[qhalf * 32 + 16 + l16][quad * 8];
    const bf16x8 bq11 = *(const bf16x8*)&qs[qhalf * 32 + 16 + l16][32 + quad * 8];
    __syncthreads();   // qs fully read -> fs reusable by epilogue

    bf16x8 ones8;
    #pragma unroll
    for (int j = 0; j < 8; j++) ones8[j] = (j < 4) ? (short)0x3F80 : (short)0;

    f32x4 of[4][2];
    #pragma unroll
    for (int dg = 0; dg < 4; dg++) {
        of[dg][0] = (f32x4){0.f, 0.f, 0.f, 0.f};
        of[dg][1] = (f32x4){0.f, 0.f, 0.f, 0.f};
    }
    f32x4 ofl0 = (f32x4){0.f, 0.f, 0.f, 0.f};
    f32x4 ofl1 = (f32x4){0.f, 0.f, 0.f, 0.f};

    // ---- per-lane global fragment bases
    // ak: K[kt*64 + kslice*16 + l16][quad*8 .. +7] (+32 for d-half 1): 16B/lane
    // av: V^T[dg*16 + l16][kt*64 + kslice*16 + quad*4 .. +3]: 8B/lane
    const unsigned short* kbase = Kp + (size_t)bh * S_LEN * DHDIM
        + (size_t)(kslice * 16 + l16) * DHDIM + quad * 8;
    const unsigned short* vbase = Vp + (size_t)bh * DHDIM * S_LEN
        + (size_t)l16 * S_LEN + kslice * 16 + quad * 4;

    // ---- prefetch tile k0
    uint4 kr0, kr1; uint2 vr0, vr1, vr2, vr3;
    {
        const unsigned short* kp = kbase + (size_t)k0 * (64 * DHDIM);
        const unsigned short* vp = vbase + k0 * 64;
        kr0 = *(const uint4*)(kp);
        kr1 = *(const uint4*)(kp + 32);
        vr0 = *(const uint2*)(vp);
        vr1 = *(const uint2*)(vp + 16 * S_LEN);
        vr2 = *(const uint2*)(vp + 32 * S_LEN);
        vr3 = *(const uint2*)(vp + 48 * S_LEN);
    }

    for (int kt = k0; kt < k1; kt++) {
        // current tile fragments (from prefetch regs)
        const bf16x8 ak0 = as_bf16x8(kr0);
        const bf16x8 ak1 = as_bf16x8(kr1);
        const uint2 cv0 = vr0, cv1 = vr1, cv2 = vr2, cv3 = vr3;

        // issue next tile's loads; latency hides under this tile's compute
        if (kt + 1 < k1) {
            const unsigned short* kp = kbase + (size_t)(kt + 1) * (64 * DHDIM);
            const unsigned short* vp = vbase + (kt + 1) * 64;
            kr0 = *(const uint4*)(kp);
            kr1 = *(const uint4*)(kp + 32);
            vr0 = *(const uint2*)(vp);
            vr1 = *(const uint2*)(vp + 16 * S_LEN);
            vr2 = *(const uint2*)(vp + 32 * S_LEN);
            vr3 = *(const uint2*)(vp + 48 * S_LEN);
        }

        // ---- St: this wave's k-slice x its two q-groups
        f32x4 sf0 = (f32x4){-M2, -M2, -M2, -M2};
        f32x4 sf1 = (f32x4){-M2, -M2, -M2, -M2};
        sf0 = __builtin_amdgcn_mfma_f32_16x16x32_bf16(ak0, bq00, sf0, 0, 0, 0);
        sf0 = __builtin_amdgcn_mfma_f32_16x16x32_bf16(ak1, bq01, sf0, 0, 0, 0);
        sf1 = __builtin_amdgcn_mfma_f32_16x16x32_bf16(ak0, bq10, sf1, 0, 0, 0);
        sf1 = __builtin_amdgcn_mfma_f32_16x16x32_bf16(ak1, bq11, sf1, 0, 0, 0);

        // ---- softmax numerator; causal zero on the diagonal tile
        const bool diag = (kt == qt);
        float p0[4], p1[4];
        #pragma unroll
        for (int r = 0; r < 4; r++) {
            p0[r] = fast_exp2(sf0[r]);
            p1[r] = fast_exp2(sf1[r]);
            if (diag) {
                const int kloc = kslice * 16 + quad * 4 + r;
                if (kloc > qhalf * 32 + l16)      p0[r] = 0.f;
                if (kloc > qhalf * 32 + 16 + l16) p1[r] = 0.f;
            }
        }
        // D-layout (k=quad*4+r, q=l16) == K16 B-fragment: P stays in regs
        const bf16x8 bp0 = pad4(packhi(p0[0], p0[1]), packhi(p0[2], p0[3]));
        const bf16x8 bp1 = pad4(packhi(p1[0], p1[1]), packhi(p1[2], p1[3]));
        ofl0 = __builtin_amdgcn_mfma_f32_16x16x32_bf16(ones8, bp0, ofl0, 0, 0, 0);
        ofl1 = __builtin_amdgcn_mfma_f32_16x16x32_bf16(ones8, bp1, ofl1, 0, 0, 0);

        // ---- PV partial over this wave's k-slice (zero-padded K)
        {
            const bf16x8 av0 = pad4(cv0.x, cv0.y);
            of[0][0] = __builtin_amdgcn_mfma_f32_16x16x32_bf16(av0, bp0, of[0][0], 0, 0, 0);
            of[0][1] = __builtin_amdgcn_mfma_f32_16x16x32_bf16(av0, bp1, of[0][1], 0, 0, 0);
            const bf16x8 av1 = pad4(cv1.x, cv1.y);
            of[1][0] = __builtin_amdgcn_mfma_f32_16x16x32_bf16(av1, bp0, of[1][0], 0, 0, 0);
            of[1][1] = __builtin_amdgcn_mfma_f32_16x16x32_bf16(av1, bp1, of[1][1], 0, 0, 0);
            const bf16x8 av2 = pad4(cv2.x, cv2.y);
            of[2][0] = __builtin_amdgcn_mfma_f32_16x16x32_bf16(av2, bp0, of[2][0], 0, 0, 0);
            of[2][1] = __builtin_amdgcn_mfma_f32_16x16x32_bf16(av2, bp1, of[2][1], 0, 0, 0);
            const bf16x8 av3 = pad4(cv3.x, cv3.y);
            of[3][0] = __builtin_amdgcn_mfma_f32_16x16x32_bf16(av3, bp0, of[3][0], 0, 0, 0);
            of[3][1] = __builtin_amdgcn_mfma_f32_16x16x32_bf16(av3, bp1, of[3][1], 0, 0, 0);
        }
    }

    // ---- cross-kslice reduction (once per block), chunked LDS tree
    __syncthreads();
    const int rb = lane * 18;
    #pragma unroll
    for (int pass = 0; pass < 2; pass++) {
        const int d0 = pass * 2;
        if (kslice >= 2) {
            float* w = fs + (qhalf * 2 + (kslice - 2)) * (64 * 18) + rb;
            #pragma unroll
            for (int d = 0; d < 2; d++)
                #pragma unroll
                for (int n2 = 0; n2 < 2; n2++)
                    #pragma unroll
                    for (int r = 0; r < 4; r++)
                        w[d * 8 + n2 * 4 + r] = of[d0 + d][n2][r];
            if (pass) { w[16] = ofl0[0]; w[17] = ofl1[0]; }
        }
        __syncthreads();
        if (kslice < 2) {
            const float* rd = fs + (qhalf * 2 + kslice) * (64 * 18) + rb;
            #pragma unroll
            for (int d = 0; d < 2; d++)
                #pragma unroll
                for (int n2 = 0; n2 < 2; n2++)
                    #pragma unroll
                    for (int r = 0; r < 4; r++)
                        of[d0 + d][n2][r] += rd[d * 8 + n2 * 4 + r];
            if (pass) { ofl0[0] += rd[16]; ofl1[0] += rd[17]; }
        }
        __syncthreads();
        if (kslice == 1) {
            float* w = fs + qhalf * (64 * 18) + rb;
            #pragma unroll
            for (int d = 0; d < 2; d++)
                #pragma unroll
                for (int n2 = 0; n2 < 2; n2++)
                    #pragma unroll
                    for (int r = 0; r < 4; r++)
                        w[d * 8 + n2 * 4 + r] = of[d0 + d][n2][r];
            if (pass) { w[16] = ofl0[0]; w[17] = ofl1[0]; }
        }
        __syncthreads();
        if (kslice == 0) {
            const float* rd = fs + qhalf * (64 * 18) + rb;
            #pragma unroll
            for (int d = 0; d < 2; d++)
                #pragma unroll
                for (int n2 = 0; n2 < 2; n2++)
                    #pragma unroll
                    for (int r = 0; r < 4; r++)
                        of[d0 + d][n2][r] += rd[d * 8 + n2 * 4 + r];
            if (pass) { ofl0[0] += rd[16]; ofl1[0] += rd[17]; }
        }
        __syncthreads();
    }

    // ---- waves kslice==0 hold full sums for their q-half: write out
    if (kslice == 0) {
        const int q0 = qt * 64 + qhalf * 32 + l16;       // n2=0 row
        const int q1 = q0 + 16;                           // n2=1 row
        if (whole) {
            const float inv0 = 1.f / ofl0[0];
            const float inv1 = 1.f / ofl1[0];
            float* o0 = O + ((size_t)bh * S_LEN + q0) * DHDIM;
            float* o1 = O + ((size_t)bh * S_LEN + q1) * DHDIM;
            #pragma unroll
            for (int dg = 0; dg < 4; dg++) {
                *(float4*)(o0 + dg * 16 + quad * 4) = make_float4(
                    of[dg][0][0] * inv0, of[dg][0][1] * inv0,
                    of[dg][0][2] * inv0, of[dg][0][3] * inv0);
                *(float4*)(o1 + dg * 16 + quad * 4) = make_float4(
                    of[dg][1][0] * inv1, of[dg][1][1] * inv1,
                    of[dg][1][2] * inv1, of[dg][1][3] * inv1);
            }
        } else {
            const int slot = ((bh * 16 + (qt - 16)) << 1) | (k0 != 0 ? 1 : 0);
            const int r0 = qhalf * 32 + l16, r1 = r0 + 16;
            if (quad == 0) {
                pL[slot * 64 + r0] = ofl0[0];
                pL[slot * 64 + r1] = ofl1[0];
            }
            float* p0p = pO + (size_t)slot * 4096 + r0 * 64;
            float* p1p = pO + (size_t)slot * 4096 + r1 * 64;
            #pragma unroll
            for (int dg = 0; dg < 4; dg++) {
                *(float4*)(p0p + dg * 16 + quad * 4) = make_float4(
                    of[dg][0][0], of[dg][0][1], of[dg][0][2], of[dg][0][3]);
                *(float4*)(p1p + dg * 16 + quad * 4) = make_float4(
                    of[dg][1][0], of[dg][1][1], of[dg][1][2], of[dg][1][3]);
            }
        }
    }
}

// ---- combine: O = (Oa + Ob) / (la + lb), per (bh, qt) for qt in [16,31]
__global__ __launch_bounds__(256) void combine(
    const float* __restrict__ pO, const float* __restrict__ pL,
    float* __restrict__ O)
{
    const int qt = 16 + blockIdx.x, bh = blockIdx.y;
    const int sa = ((bh * 16 + (qt - 16)) << 1), sb = sa | 1;
    const float* A = pO + (size_t)sa * 4096;
    const float* B = pO + (size_t)sb * 4096;
    float* out = O + ((size_t)bh * S_LEN + qt * 64) * DHDIM;
    #pragma unroll
    for (int k = 0; k < 4; k++) {
        int c = threadIdx.x + k * 256;     // float4 chunk 0..1023
        int row = c >> 4;
        float inv = 1.f / (pL[sa * 64 + row] + pL[sb * 64 + row]);
        float4 a = *(const float4*)(A + c * 4);
        float4 b = *(const float4*)(B + c * 4);
        *(float4*)(out + c * 4) = make_float4(
            (a.x + b.x) * inv, (a.y + b.y) * inv,
            (a.z + b.z) * inv, (a.w + b.w) * inv);
    }
}

// ---- fallback kernels (whole-row blocks), used when ws too small
template <bool PRE>
__global__ __launch_bounds__(256) void fattn_kernel(
    const void* __restrict__ Qp, const void* __restrict__ Kp,
    const void* __restrict__ Vp, float* __restrict__ O)
{
    __shared__ unsigned short smem[192 * LDP];
    unsigned short (*ks)[LDP]  = (unsigned short(*)[LDP])smem;
    unsigned short (*vts)[LDP] = (unsigned short(*)[LDP])(smem + 64 * LDP);
    unsigned short (*qs)[LDP]  = (unsigned short(*)[LDP])(smem + 128 * LDP);
    unsigned short (*pst)[LDP] = qs;

    const int id = blockIdx.y * 32 + blockIdx.x;
    const int g  = id >> 8;
    const int r8 = id & 255;
    const int bh = r8 >> 3;
    const int s8 = r8 & 7;
    const int qt = (g == 0) ? 31 - 2 * s8 : (g == 1) ? 2 * s8
                 : (g == 2) ? 30 - 2 * s8 : 2 * s8 + 1;

    const int tid = threadIdx.x;
    const int wave = tid >> 6, lane = tid & 63;
    const int quad = lane >> 4, l16 = lane & 15;

    if constexpr (PRE) {
        const unsigned short* src = (const unsigned short*)Qp
            + ((size_t)bh * S_LEN + qt * 64) * DHDIM;
        for (int c = tid; c < 512; c += 256) {
            int row = c >> 3, c8 = (c & 7) * 8;
            *(uint4*)&qs[row][c8] = *(const uint4*)(src + row * DHDIM + c8);
        }
    } else {
        const float* src = (const float*)Qp + ((size_t)bh * S_LEN + qt * 64) * DHDIM;
        for (int c = tid; c < 512; c += 256) {
            int row = c >> 3, c8 = (c & 7) * 8;
            float f[8]; ld8(src + row * DHDIM + c8, f);
            *(uint4*)&qs[row][c8] = pack8(f, QSCALE);
        }
    }
    __syncthreads();

    const int prow = wave * 16 + l16;
    const bf16x8 bq0 = *(const bf16x8*)&qs[prow][quad * 8];
    const bf16x8 bq1 = *(const bf16x8*)&qs[prow][32 + quad * 8];

    float l_p = 0.f;
    f32x4 of[4];
    #pragma unroll
    for (int n = 0; n < 4; n++) of[n] = (f32x4){0.f, 0.f, 0.f, 0.f};

    for (int kt = 0; kt <= qt; kt++) {
        __syncthreads();
        if constexpr (PRE) {
            const unsigned short* ksrc = (const unsigned short*)Kp
                + ((size_t)bh * S_LEN + kt * 64) * DHDIM;
            const unsigned short* vsrc = (const unsigned short*)Vp
                + (size_t)bh * DHDIM * S_LEN + kt * 64;
            for (int c = tid; c < 512; c += 256) {
                int row = c >> 3, c8 = (c & 7) * 8;
                *(uint4*)&ks[row][c8]  = *(const uint4*)(ksrc + row * DHDIM + c8);
                *(uint4*)&vts[row][c8] = *(const uint4*)(vsrc + (size_t)row * S_LEN + c8);
            }
        } else {
            const float* ksrc = (const float*)Kp + ((size_t)bh * S_LEN + kt * 64) * DHDIM;
            const float* vsrc = (const float*)Vp + ((size_t)bh * S_LEN + kt * 64) * DHDIM;
            for (int c = tid; c < 512; c += 256) {
                int row = c >> 3, c8 = (c & 7) * 8;
                float f[8];
                ld8(ksrc + row * DHDIM + c8, f);
                *(uint4*)&ks[row][c8] = pack8(f, 1.0f);
                ld8(vsrc + row * DHDIM + c8, f);
                #pragma unroll
                for (int j = 0; j < 8; j++) vts[c8 + j][row] = f2bf(f[j]);
            }
        }
        __syncthreads();

        f32x4 sf[4];
        #pragma unroll
        for (int n = 0; n < 4; n++) {
            bf16x8 ak0 = *(const bf16x8*)&ks[n * 16 + l16][quad * 8];
            bf16x8 ak1 = *(const bf16x8*)&ks[n * 16 + l16][32 + quad * 8];
            sf[n] = (f32x4){-M2, -M2, -M2, -M2};
            sf[n] = __builtin_amdgcn_mfma_f32_16x16x32_bf16(ak0, bq0, sf[n], 0, 0, 0);
            sf[n] = __builtin_amdgcn_mfma_f32_16x16x32_bf16(ak1, bq1, sf[n], 0, 0, 0);
        }

        const bool diag = (kt == qt);
        #pragma unroll
        for (int n = 0; n < 4; n++) {
            float p[4];
            #pragma unroll
            for (int r = 0; r < 4; r++) {
                p[r] = fast_exp2(sf[n][r]);
                if (diag && (n * 16 + quad * 4 + r > prow)) p[r] = 0.f;
                l_p += p[r];
            }
            uint2 dw;
            dw.x = packhi(p[0], p[1]);
            dw.y = packhi(p[2], p[3]);
            *(uint2*)&pst[prow][n * 16 + quad * 4] = dw;
        }
        asm volatile("s_waitcnt lgkmcnt(0)" ::: "memory");

        bf16x8 bp0 = *(const bf16x8*)&pst[prow][quad * 8];
        bf16x8 bp1 = *(const bf16x8*)&pst[prow][32 + quad * 8];
        #pragma unroll
        for (int n = 0; n < 4; n++) {
            bf16x8 av0 = *(const bf16x8*)&vts[n * 16 + l16][quad * 8];
            bf16x8 av1 = *(const bf16x8*)&vts[n * 16 + l16][32 + quad * 8];
            of[n] = __builtin_amdgcn_mfma_f32_16x16x32_bf16(av0, bp0, of[n], 0, 0, 0);
            of[n] = __builtin_amdgcn_mfma_f32_16x16x32_bf16(av1, bp1, of[n], 0, 0, 0);
        }
    }

    l_p += __shfl_xor(l_p, 16);
    l_p += __shfl_xor(l_p, 32);
    const float inv = 1.f / l_p;
    float* op = O + ((size_t)bh * S_LEN + qt * 64 + prow) * DHDIM;
    #pragma unroll
    for (int n = 0; n < 4; n++)
        *(float4*)(op + n * 16 + quad * 4) = make_float4(
            of[n][0] * inv, of[n][1] * inv, of[n][2] * inv, of[n][3] * inv);
}

extern "C" void kernel_launch(void* const* d_in, const int* in_sizes, int n_in,
                              void* d_out, int out_size, void* d_ws, size_t ws_size,
                              hipStream_t stream) {
    const float* Q = (const float*)d_in[0];
    const float* K = (const float*)d_in[1];
    const float* V = (const float*)d_in[2];
    // d_in[3] = causal mask: analytic, not read.
    float* O = (float*)d_out;
    const size_t N = (size_t)NHEADS * S_LEN * DHDIM;      // 4,194,304 elems
    const size_t prepB  = 3 * N * sizeof(unsigned short); // 25.2 MB
    // 1024 partial slots (qt>=16 halves): O-partials + l
    const size_t partB  = (size_t)1024 * (4096 + 64) * sizeof(float); // 17.0 MB

    if (d_ws && ws_size >= prepB + partB) {
        unsigned short* qb  = (unsigned short*)d_ws;
        unsigned short* kb  = qb + N;
        unsigned short* vtb = kb + N;
        float* pO = (float*)((char*)d_ws + prepB);
        float* pL = pO + (size_t)1024 * 4096;
        prep<<<dim3(S_LEN / 64, NHEADS), 256, 0, stream>>>(Q, K, V, qb, kb, vtb);
        fattn_splitk<<<dim3(32, 48), 512, 0, stream>>>(qb, kb, vtb, pO, pL, O);
        combine<<<dim3(16, 32), 256, 0, stream>>>(pO, pL, O);
    } else if (d_ws && ws_size >= prepB) {
        unsigned short* qb  = (unsigned short*)d_ws;
        unsigned short* kb  = qb + N;
        unsigned short* vtb = kb + N;
        prep<<<dim3(S_LEN / 64, NHEADS), 256, 0, stream>>>(Q, K, V, qb, kb, vtb);
        fattn_kernel<true><<<dim3(32, 32), 256, 0, stream>>>(qb, kb, vtb, O);
    } else {
        fattn_kernel<false><<<dim3(32, 32), 256, 0, stream>>>(Q, K, V, O);
    }
}

// Round 6
// 140.960 us; speedup vs baseline: 1.4504x; 1.4504x over previous
//
#include <hip/hip_runtime.h>

// Causal MHA: B=2, H=16, S=2048, DH=64. fp32 in/out. bf16 MFMA inside.
// R15: uniform work items + setprio, on the PROVEN R12 core (43.9us).
// R14 post-mortem: zero-barrier direct-global = 104us (latency exposed
// per-wave; LDS staging+barriers amortize it -- keep them). New facts:
// (a) ~84us of every run is harness workspace-poison fills (fixed);
// (b) occupancy ~35% in ALL variants regardless of LDS capacity ->
// limiter is work granularity (items 1..16 tiles, avg 11, tail on max).
// Fix: split every q-row into pieces of <=11 tiles: qt>=22 -> 3 pieces,
// 11<=qt<=21 -> 2, qt<=10 whole. 63 items/bh (len 6..11 + tiny wholes),
// 2016 blocks, static LPT table. Combine sums 2-3 partials (fixed-max
// softmax => exact). T5 s_setprio(1) around MFMA cluster (role-diverse
// co-resident blocks). Core kept verbatim from R12: 256thr/4-wave prow
// scheme, LDS K/V staging + reg prefetch, 2 barriers/tile, in-LDS Pt,
// l via ones-MFMA, fast_exp2, -M2 C-init, v_perm pack, LDP=72, prep
// (bf16 Q*0.125*log2e, K, V^T dword-swizzled), analytic causal mask.

#define S_LEN  2048
#define DHDIM  64
#define NHEADS 32   // B*H
#define LDP    72   // padded LDS row length in shorts (144B = 9*16B)
#define M2     23.083120654223414f   // 16 * log2(e)
#define QSCALE 0.18033688011117658f  // 0.125 * log2(e)
#define NSLOT  52   // partial slots per bh

typedef __attribute__((ext_vector_type(8))) short bf16x8;
typedef __attribute__((ext_vector_type(4))) float f32x4;

// rank table: 63 items per bh, LPT (desc length) order.
// entry = qt<<24 | k0<<16 | k1<<8 | slot  (slot 255 = whole row, direct O)
#define RT(qt,k0,k1,sl) ((unsigned)(qt)<<24 | (unsigned)(k0)<<16 | (unsigned)(k1)<<8 | (unsigned)(sl))
__device__ __constant__ unsigned RTAB[63] = {
    RT(31,0,11,49),  RT(31,11,22,50), RT(30,0,11,46),  RT(21,0,11,20),
    RT(21,11,22,21), RT(20,0,11,18),  RT(10,0,11,255),
    RT(31,22,32,51), RT(30,11,21,47), RT(30,21,31,48), RT(29,0,10,43),
    RT(29,10,20,44), RT(29,20,30,45), RT(28,0,10,40),  RT(28,10,20,41),
    RT(27,0,10,37),  RT(20,11,21,19), RT(19,0,10,16),  RT(19,10,20,17),
    RT(18,0,10,14),  RT(9,0,10,255),
    RT(28,20,29,42), RT(27,10,19,38), RT(27,19,28,39), RT(26,0,9,34),
    RT(26,9,18,35),  RT(26,18,27,36), RT(25,0,9,31),   RT(25,9,18,32),
    RT(24,0,9,28),   RT(18,10,19,15), RT(17,0,9,12),   RT(17,9,18,13),
    RT(16,0,9,10),   RT(8,0,9,255),
    RT(25,18,26,33), RT(24,9,17,29),  RT(24,17,25,30), RT(23,0,8,25),
    RT(23,8,16,26),  RT(23,16,24,27), RT(22,0,8,22),   RT(22,8,16,23),
    RT(16,9,17,11),  RT(15,0,8,8),    RT(15,8,16,9),   RT(14,0,8,6),
    RT(7,0,8,255),
    RT(22,16,23,24), RT(14,8,15,7),   RT(13,0,7,4),    RT(13,7,14,5),
    RT(12,0,7,2),    RT(6,0,7,255),
    RT(12,7,13,3),   RT(11,0,6,0),    RT(11,6,12,1),   RT(5,0,6,255),
    RT(4,0,5,255),   RT(3,0,4,255),   RT(2,0,3,255),   RT(1,0,2,255),
    RT(0,0,1,255)};

__device__ __forceinline__ float fast_exp2(float x) {
#if __has_builtin(__builtin_amdgcn_exp2f)
    return __builtin_amdgcn_exp2f(x);
#else
    return exp2f(x);
#endif
}
__device__ __forceinline__ unsigned short f2bf(float f) { // RNE
    unsigned u = __float_as_uint(f);
    return (unsigned short)((u + 0x7fffu + ((u >> 16) & 1u)) >> 16);
}
__device__ __forceinline__ void ld8(const float* p, float* f) {
    float4 a = *(const float4*)p, b = *(const float4*)(p + 4);
    f[0]=a.x; f[1]=a.y; f[2]=a.z; f[3]=a.w; f[4]=b.x; f[5]=b.y; f[6]=b.z; f[7]=b.w;
}
__device__ __forceinline__ uint4 pack8(const float* f, float scale) {
    union { uint4 v; unsigned short s[8]; } w;
    #pragma unroll
    for (int j = 0; j < 8; j++) w.s[j] = f2bf(f[j] * scale);
    return w.v;
}
// combine high-16s of two floats into one dword: [lo16=a.hi16, hi16=b.hi16]
__device__ __forceinline__ unsigned packhi(float a, float b) {
#if __has_builtin(__builtin_amdgcn_perm)
    return __builtin_amdgcn_perm(__float_as_uint(b), __float_as_uint(a), 0x07060302u);
#else
    return (__float_as_uint(a) >> 16) | (__float_as_uint(b) & 0xffff0000u);
#endif
}

// ---- pre-pass: per block (st, bh): V 64x64 tile -> bf16 V^T tile, plus a
// 4096-elem chunk of Q (scaled) and K -> bf16.
__global__ __launch_bounds__(256) void prep(
    const float* __restrict__ Qf, const float* __restrict__ Kf,
    const float* __restrict__ Vf, unsigned short* __restrict__ qb,
    unsigned short* __restrict__ kb, unsigned short* __restrict__ vtb)
{
    const int st = blockIdx.x, bh = blockIdx.y;
    __shared__ unsigned lt32[64][LDP / 2];   // dword view: 36 dwords/row
    const float* vp = Vf + ((size_t)bh * S_LEN + st * 64) * DHDIM;
    {
        const int c = threadIdx.x;
        const int sp = c >> 3;            // s-pair index 0..31
        const int d0 = (c & 7) * 8;
        float fa[8], fb[8];
        ld8(vp + (2 * sp) * DHDIM + d0, fa);
        ld8(vp + (2 * sp + 1) * DHDIM + d0, fb);
        #pragma unroll
        for (int j = 0; j < 8; j++) {
            int d = d0 + j;
            int colw = (sp & 3) | ((((sp >> 2) ^ (d >> 3)) & 7) << 2);
            lt32[d][colw] = (unsigned)f2bf(fa[j]) | ((unsigned)f2bf(fb[j]) << 16);
        }
    }
    size_t off = ((size_t)(bh * 32 + st) * 4096) + (size_t)threadIdx.x * 16;
    float f[8];
    ld8(Qf + off, f);     *(uint4*)(qb + off)     = pack8(f, QSCALE);
    ld8(Qf + off + 8, f); *(uint4*)(qb + off + 8) = pack8(f, QSCALE);
    ld8(Kf + off, f);     *(uint4*)(kb + off)     = pack8(f, 1.0f);
    ld8(Kf + off + 8, f); *(uint4*)(kb + off + 8) = pack8(f, 1.0f);
    __syncthreads();
    unsigned short* op = vtb + (size_t)bh * DHDIM * S_LEN + st * 64;
    for (int c = threadIdx.x; c < 512; c += 256) {
        int d = c >> 3, q = c & 7;
        int colw = ((q ^ (d >> 3)) & 7) << 2;
        *(uint4*)(op + (size_t)d * S_LEN + q * 8) = *(const uint4*)&lt32[d][colw];
    }
}

// ---- main: block = (bh, rank). rank -> (qt, k0, k1, slot) via RTAB.
// R12 core: 256 threads, 4 waves, prow scheme, LDS staging + reg prefetch.
__global__ __launch_bounds__(256) void fattn_splitk(
    const unsigned short* __restrict__ Qp, const unsigned short* __restrict__ Kp,
    const unsigned short* __restrict__ Vp,
    float* __restrict__ pO, float* __restrict__ pL, float* __restrict__ O)
{
    __shared__ unsigned short smem[192 * LDP]; // 27.6 KB -> 5 blocks/CU
    unsigned short (*ks)[LDP]  = (unsigned short(*)[LDP])smem;
    unsigned short (*vts)[LDP] = (unsigned short(*)[LDP])(smem + 64 * LDP);
    unsigned short (*qs)[LDP]  = (unsigned short(*)[LDP])(smem + 128 * LDP);
    unsigned short (*pst)[LDP] = qs; // overlay: wave w touches only rows w*16..+15

    const int bh   = blockIdx.x;           // 0..31
    const unsigned e = RTAB[blockIdx.y];   // 0..62, longest-first
    const int qt   = e >> 24;
    const int k0   = (e >> 16) & 255;
    const int k1   = (e >> 8) & 255;
    const int sl   = e & 255;
    const bool whole = (sl == 255);

    const int tid = threadIdx.x;
    const int wave = tid >> 6, lane = tid & 63;
    const int quad = lane >> 4, l16 = lane & 15;

    // ---- stage Q tile (bf16, pre-scaled by prep)
    {
        const unsigned short* src = Qp + ((size_t)bh * S_LEN + qt * 64) * DHDIM;
        for (int c = tid; c < 512; c += 256) {
            int row = c >> 3, c8 = (c & 7) * 8;
            *(uint4*)&qs[row][c8] = *(const uint4*)(src + row * DHDIM + c8);
        }
    }
    __syncthreads();

    const int prow = wave * 16 + l16; // this lane's q-row (transposed scheme)
    const bf16x8 bq0 = *(const bf16x8*)&qs[prow][quad * 8];
    const bf16x8 bq1 = *(const bf16x8*)&qs[prow][32 + quad * 8];

    bf16x8 ones;
    #pragma unroll
    for (int j = 0; j < 8; j++) ones[j] = (short)0x3F80; // bf16 1.0

    f32x4 of[4];
    f32x4 of_l = (f32x4){0.f, 0.f, 0.f, 0.f}; // ones-row * Pt = l per q-col
    #pragma unroll
    for (int n = 0; n < 4; n++) of[n] = (f32x4){0.f, 0.f, 0.f, 0.f};

    // ---- T14 prefetch: staging registers for the next K/V tile
    const unsigned short* Kbh = Kp + (size_t)bh * S_LEN * DHDIM;
    const unsigned short* Vbh = Vp + (size_t)bh * DHDIM * S_LEN;
    const int sr = tid >> 3, sc = (tid & 7) * 8;   // rows sr, sr+32
    uint4 kr0, kr1, vr0, vr1;
    {
        const unsigned short* ksrc = Kbh + (size_t)k0 * 64 * DHDIM;
        const unsigned short* vsrc = Vbh + k0 * 64;
        kr0 = *(const uint4*)(ksrc + sr * DHDIM + sc);
        kr1 = *(const uint4*)(ksrc + (sr + 32) * DHDIM + sc);
        vr0 = *(const uint4*)(vsrc + (size_t)sr * S_LEN + sc);
        vr1 = *(const uint4*)(vsrc + (size_t)(sr + 32) * S_LEN + sc);
    }

    for (int kt = k0; kt < k1; kt++) {
        __syncthreads(); // prior iter done with ks/vts

        // write current prefetched tile to LDS (vmcnt wait folds in here)
        *(uint4*)&ks[sr][sc]       = kr0;
        *(uint4*)&ks[sr + 32][sc]  = kr1;
        *(uint4*)&vts[sr][sc]      = vr0;
        *(uint4*)&vts[sr + 32][sc] = vr1;

        // issue next tile's global loads; latency hides under compute below
        if (kt + 1 < k1) {
            const unsigned short* ksrc = Kbh + (size_t)(kt + 1) * 64 * DHDIM;
            const unsigned short* vsrc = Vbh + (kt + 1) * 64;
            kr0 = *(const uint4*)(ksrc + sr * DHDIM + sc);
            kr1 = *(const uint4*)(ksrc + (sr + 32) * DHDIM + sc);
            vr0 = *(const uint4*)(vsrc + (size_t)sr * S_LEN + sc);
            vr1 = *(const uint4*)(vsrc + (size_t)(sr + 32) * S_LEN + sc);
        }
        __syncthreads();

        // ---- St tile n; C-init = -M2 folds the softmax subtract
        __builtin_amdgcn_s_setprio(1);
        f32x4 sf[4];
        #pragma unroll
        for (int n = 0; n < 4; n++) {
            bf16x8 ak0 = *(const bf16x8*)&ks[n * 16 + l16][quad * 8];
            bf16x8 ak1 = *(const bf16x8*)&ks[n * 16 + l16][32 + quad * 8];
            sf[n] = (f32x4){-M2, -M2, -M2, -M2};
            sf[n] = __builtin_amdgcn_mfma_f32_16x16x32_bf16(ak0, bq0, sf[n], 0, 0, 0);
            sf[n] = __builtin_amdgcn_mfma_f32_16x16x32_bf16(ak1, bq1, sf[n], 0, 0, 0);
        }
        __builtin_amdgcn_s_setprio(0);

        // ---- p = exp2(sf), causal zero (diag tile), pack Pt (l via MFMA below)
        const bool diag = (kt == qt);
        #pragma unroll
        for (int n = 0; n < 4; n++) {
            float p[4];
            #pragma unroll
            for (int r = 0; r < 4; r++) {
                p[r] = fast_exp2(sf[n][r]);
                if (diag && (n * 16 + quad * 4 + r > prow)) p[r] = 0.f;
            }
            uint2 dw;
            dw.x = packhi(p[0], p[1]); // bf16 truncation via byte-select
            dw.y = packhi(p[2], p[3]);
            *(uint2*)&pst[prow][n * 16 + quad * 4] = dw;
        }
        asm volatile("s_waitcnt lgkmcnt(0)" ::: "memory"); // wave-local Pt fence

        __builtin_amdgcn_s_setprio(1);
        bf16x8 bp0 = *(const bf16x8*)&pst[prow][quad * 8];
        bf16x8 bp1 = *(const bf16x8*)&pst[prow][32 + quad * 8];
        of_l = __builtin_amdgcn_mfma_f32_16x16x32_bf16(ones, bp0, of_l, 0, 0, 0);
        of_l = __builtin_amdgcn_mfma_f32_16x16x32_bf16(ones, bp1, of_l, 0, 0, 0);
        #pragma unroll
        for (int n = 0; n < 4; n++) {
            bf16x8 av0 = *(const bf16x8*)&vts[n * 16 + l16][quad * 8];
            bf16x8 av1 = *(const bf16x8*)&vts[n * 16 + l16][32 + quad * 8];
            of[n] = __builtin_amdgcn_mfma_f32_16x16x32_bf16(av0, bp0, of[n], 0, 0, 0);
            of[n] = __builtin_amdgcn_mfma_f32_16x16x32_bf16(av1, bp1, of[n], 0, 0, 0);
        }
        __builtin_amdgcn_s_setprio(0);
    }

    if (whole) {
        // short row: normalize and write O directly, no partial traffic
        const float inv = 1.f / of_l[0];
        float* op = O + ((size_t)bh * S_LEN + qt * 64 + prow) * DHDIM;
        #pragma unroll
        for (int n = 0; n < 4; n++)
            *(float4*)(op + n * 16 + quad * 4) = make_float4(
                of[n][0] * inv, of[n][1] * inv, of[n][2] * inv, of[n][3] * inv);
    } else {
        // piece: write unnormalized partial + per-row l (fixed-max softmax
        // => partials combine exactly by summation in the combine kernel)
        const int slot = bh * NSLOT + sl;
        if (quad == 0) pL[slot * 64 + prow] = of_l[0];
        float* op = pO + (size_t)slot * 4096 + prow * 64;
        #pragma unroll
        for (int n = 0; n < 4; n++)
            *(float4*)(op + n * 16 + quad * 4) =
                make_float4(of[n][0], of[n][1], of[n][2], of[n][3]);
    }
}

// ---- combine: O = sum(Oi) / sum(li), per (bh, qt) for qt in [11,31]
__global__ __launch_bounds__(256) void combine(
    const float* __restrict__ pO, const float* __restrict__ pL,
    float* __restrict__ O)
{
    const int qt = 11 + blockIdx.x, bh = blockIdx.y;
    int base, cnt;
    if (qt < 22) { base = (qt - 11) * 2;      cnt = 2; }
    else         { base = 22 + 3 * (qt - 22); cnt = 3; }
    const int sb = bh * NSLOT + base;
    const float* A = pO + (size_t)sb * 4096;
    float* out = O + ((size_t)bh * S_LEN + qt * 64) * DHDIM;
    #pragma unroll
    for (int k = 0; k < 4; k++) {
        int c = threadIdx.x + k * 256;     // float4 chunk 0..1023
        int row = c >> 4;
        float l = pL[sb * 64 + row] + pL[(sb + 1) * 64 + row];
        float4 a = *(const float4*)(A + c * 4);
        float4 b = *(const float4*)(A + 4096 + c * 4);
        float4 s = make_float4(a.x + b.x, a.y + b.y, a.z + b.z, a.w + b.w);
        if (cnt == 3) {
            l += pL[(sb + 2) * 64 + row];
            float4 d = *(const float4*)(A + 8192 + c * 4);
            s = make_float4(s.x + d.x, s.y + d.y, s.z + d.z, s.w + d.w);
        }
        float inv = 1.f / l;
        *(float4*)(out + c * 4) = make_float4(
            s.x * inv, s.y * inv, s.z * inv, s.w * inv);
    }
}

// ---- fallback kernels (whole-row blocks), used when ws too small
template <bool PRE>
__global__ __launch_bounds__(256) void fattn_kernel(
    const void* __restrict__ Qp, const void* __restrict__ Kp,
    const void* __restrict__ Vp, float* __restrict__ O)
{
    __shared__ unsigned short smem[192 * LDP];
    unsigned short (*ks)[LDP]  = (unsigned short(*)[LDP])smem;
    unsigned short (*vts)[LDP] = (unsigned short(*)[LDP])(smem + 64 * LDP);
    unsigned short (*qs)[LDP]  = (unsigned short(*)[LDP])(smem + 128 * LDP);
    unsigned short (*pst)[LDP] = qs;

    const int id = blockIdx.y * 32 + blockIdx.x;
    const int g  = id >> 8;
    const int r8 = id & 255;
    const int bh = r8 >> 3;
    const int s8 = r8 & 7;
    const int qt = (g == 0) ? 31 - 2 * s8 : (g == 1) ? 2 * s8
                 : (g == 2) ? 30 - 2 * s8 : 2 * s8 + 1;

    const int tid = threadIdx.x;
    const int wave = tid >> 6, lane = tid & 63;
    const int quad = lane >> 4, l16 = lane & 15;

    if constexpr (PRE) {
        const unsigned short* src = (const unsigned short*)Qp
            + ((size_t)bh * S_LEN + qt * 64) * DHDIM;
        for (int c = tid; c < 512; c += 256) {
            int row = c >> 3, c8 = (c & 7) * 8;
            *(uint4*)&qs[row][c8] = *(const uint4*)(src + row * DHDIM + c8);
        }
    } else {
        const float* src = (const float*)Qp + ((size_t)bh * S_LEN + qt * 64) * DHDIM;
        for (int c = tid; c < 512; c += 256) {
            int row = c >> 3, c8 = (c & 7) * 8;
            float f[8]; ld8(src + row * DHDIM + c8, f);
            *(uint4*)&qs[row][c8] = pack8(f, QSCALE);
        }
    }
    __syncthreads();

    const int prow = wave * 16 + l16;
    const bf16x8 bq0 = *(const bf16x8*)&qs[prow][quad * 8];
    const bf16x8 bq1 = *(const bf16x8*)&qs[prow][32 + quad * 8];

    float l_p = 0.f;
    f32x4 of[4];
    #pragma unroll
    for (int n = 0; n < 4; n++) of[n] = (f32x4){0.f, 0.f, 0.f, 0.f};

    for (int kt = 0; kt <= qt; kt++) {
        __syncthreads();
        if constexpr (PRE) {
            const unsigned short* ksrc = (const unsigned short*)Kp
                + ((size_t)bh * S_LEN + kt * 64) * DHDIM;
            const unsigned short* vsrc = (const unsigned short*)Vp
                + (size_t)bh * DHDIM * S_LEN + kt * 64;
            for (int c = tid; c < 512; c += 256) {
                int row = c >> 3, c8 = (c & 7) * 8;
                *(uint4*)&ks[row][c8]  = *(const uint4*)(ksrc + row * DHDIM + c8);
                *(uint4*)&vts[row][c8] = *(const uint4*)(vsrc + (size_t)row * S_LEN + c8);
            }
        } else {
            const float* ksrc = (const float*)Kp + ((size_t)bh * S_LEN + kt * 64) * DHDIM;
            const float* vsrc = (const float*)Vp + ((size_t)bh * S_LEN + kt * 64) * DHDIM;
            for (int c = tid; c < 512; c += 256) {
                int row = c >> 3, c8 = (c & 7) * 8;
                float f[8];
                ld8(ksrc + row * DHDIM + c8, f);
                *(uint4*)&ks[row][c8] = pack8(f, 1.0f);
                ld8(vsrc + row * DHDIM + c8, f);
                #pragma unroll
                for (int j = 0; j < 8; j++) vts[c8 + j][row] = f2bf(f[j]);
            }
        }
        __syncthreads();

        f32x4 sf[4];
        #pragma unroll
        for (int n = 0; n < 4; n++) {
            bf16x8 ak0 = *(const bf16x8*)&ks[n * 16 + l16][quad * 8];
            bf16x8 ak1 = *(const bf16x8*)&ks[n * 16 + l16][32 + quad * 8];
            sf[n] = (f32x4){-M2, -M2, -M2, -M2};
            sf[n] = __builtin_amdgcn_mfma_f32_16x16x32_bf16(ak0, bq0, sf[n], 0, 0, 0);
            sf[n] = __builtin_amdgcn_mfma_f32_16x16x32_bf16(ak1, bq1, sf[n], 0, 0, 0);
        }

        const bool diag = (kt == qt);
        #pragma unroll
        for (int n = 0; n < 4; n++) {
            float p[4];
            #pragma unroll
            for (int r = 0; r < 4; r++) {
                p[r] = fast_exp2(sf[n][r]);
                if (diag && (n * 16 + quad * 4 + r > prow)) p[r] = 0.f;
                l_p += p[r];
            }
            uint2 dw;
            dw.x = packhi(p[0], p[1]);
            dw.y = packhi(p[2], p[3]);
            *(uint2*)&pst[prow][n * 16 + quad * 4] = dw;
        }
        asm volatile("s_waitcnt lgkmcnt(0)" ::: "memory");

        bf16x8 bp0 = *(const bf16x8*)&pst[prow][quad * 8];
        bf16x8 bp1 = *(const bf16x8*)&pst[prow][32 + quad * 8];
        #pragma unroll
        for (int n = 0; n < 4; n++) {
            bf16x8 av0 = *(const bf16x8*)&vts[n * 16 + l16][quad * 8];
            bf16x8 av1 = *(const bf16x8*)&vts[n * 16 + l16][32 + quad * 8];
            of[n] = __builtin_amdgcn_mfma_f32_16x16x32_bf16(av0, bp0, of[n], 0, 0, 0);
            of[n] = __builtin_amdgcn_mfma_f32_16x16x32_bf16(av1, bp1, of[n], 0, 0, 0);
        }
    }

    l_p += __shfl_xor(l_p, 16);
    l_p += __shfl_xor(l_p, 32);
    const float inv = 1.f / l_p;
    float* op = O + ((size_t)bh * S_LEN + qt * 64 + prow) * DHDIM;
    #pragma unroll
    for (int n = 0; n < 4; n++)
        *(float4*)(op + n * 16 + quad * 4) = make_float4(
            of[n][0] * inv, of[n][1] * inv, of[n][2] * inv, of[n][3] * inv);
}

extern "C" void kernel_launch(void* const* d_in, const int* in_sizes, int n_in,
                              void* d_out, int out_size, void* d_ws, size_t ws_size,
                              hipStream_t stream) {
    const float* Q = (const float*)d_in[0];
    const float* K = (const float*)d_in[1];
    const float* V = (const float*)d_in[2];
    // d_in[3] = causal mask: analytic, not read.
    float* O = (float*)d_out;
    const size_t N = (size_t)NHEADS * S_LEN * DHDIM;      // 4,194,304 elems
    const size_t prepB  = 3 * N * sizeof(unsigned short); // 25.2 MB
    // 52 partial slots per bh (qt>=11 pieces): O-partials + l
    const size_t partB  = (size_t)NSLOT * 32 * (4096 + 64) * sizeof(float); // 27.7 MB

    if (d_ws && ws_size >= prepB + partB) {
        unsigned short* qb  = (unsigned short*)d_ws;
        unsigned short* kb  = qb + N;
        unsigned short* vtb = kb + N;
        float* pO = (float*)((char*)d_ws + prepB);
        float* pL = pO + (size_t)NSLOT * 32 * 4096;
        prep<<<dim3(S_LEN / 64, NHEADS), 256, 0, stream>>>(Q, K, V, qb, kb, vtb);
        fattn_splitk<<<dim3(32, 63), 256, 0, stream>>>(qb, kb, vtb, pO, pL, O);
        combine<<<dim3(21, 32), 256, 0, stream>>>(pO, pL, O);
    } else if (d_ws && ws_size >= prepB) {
        unsigned short* qb  = (unsigned short*)d_ws;
        unsigned short* kb  = qb + N;
        unsigned short* vtb = kb + N;
        prep<<<dim3(S_LEN / 64, NHEADS), 256, 0, stream>>>(Q, K, V, qb, kb, vtb);
        fattn_kernel<true><<<dim3(32, 32), 256, 0, stream>>>(qb, kb, vtb, O);
    } else {
        fattn_kernel<false><<<dim3(32, 32), 256, 0, stream>>>(Q, K, V, O);
    }
}